// Round 17
// baseline (637.286 us; speedup 1.0000x reference)
//
#include <hip/hip_runtime.h>
#include <hip/hip_bf16.h>

typedef __attribute__((ext_vector_type(8))) short bf16x8;
typedef __attribute__((ext_vector_type(4))) float f32x4;

#define N_OUT 65536
#define CIN   256
#define COUT  512
#define BM    128
#define BN    256
#define BK    32
#define NKS   64    // 2048 / 32 K-steps

__device__ __forceinline__ unsigned short f2bf(float f) {
  union { __hip_bfloat16 h; unsigned short u; } c;
  c.h = __float2bfloat16(f);
  return c.u;
}

__device__ __forceinline__ float bf2f(unsigned short u) {
  union { unsigned int i; float f; } c;
  c.i = ((unsigned int)u) << 16;
  return c.f;
}

__device__ __forceinline__ bf16x8 pack8(f32x4 a, f32x4 b) {
  unsigned short u[8];
  u[0] = f2bf(a.x); u[1] = f2bf(a.y); u[2] = f2bf(a.z); u[3] = f2bf(a.w);
  u[4] = f2bf(b.x); u[5] = f2bf(b.y); u[6] = f2bf(b.z); u[7] = f2bf(b.w);
  return *reinterpret_cast<bf16x8*>(u);
}

__device__ __forceinline__ void gload_lds16u(const unsigned short* g, unsigned short* l) {
  __builtin_amdgcn_global_load_lds(
      (const __attribute__((address_space(1))) void*)g,
      (__attribute__((address_space(3))) void*)l, 16, 0, 0);
}

// --- weight prep: W[k][n] f32 -> Wt bf16 tiled [kb][slot][n][w]
__global__ void wprep_kernel(const float* __restrict__ W, unsigned short* __restrict__ Wt) {
  int idx = blockIdx.x * blockDim.x + threadIdx.x;
  if (idx >= 64 * 4 * COUT) return;
  int n  = idx & (COUT - 1);
  int s  = (idx >> 9) & 3;
  int kb = idx >> 11;
  unsigned short tmp[8];
#pragma unroll
  for (int w = 0; w < 8; ++w)
    tmp[w] = f2bf(W[(size_t)(kb * 32 + s * 8 + w) * COUT + n]);
  *reinterpret_cast<bf16x8*>(Wt + ((size_t)kb * 16384 + s * 4096 + n * 8)) =
      *reinterpret_cast<bf16x8*>(tmp);
}

// --- main GEMM: A direct global->register (2-deep X/Y sets, consumed two
//     barriers after issue -> hard counted vmcnt(18)); B via global_load_lds
//     3-ring (keeps the R16 one-barrier/step skeleton). LDS/step 88->48KB.
__global__ __launch_bounds__(512, 2) void gemm_kernel(
    const float* __restrict__ data,
    const int*   __restrict__ neigh,
    const unsigned short* __restrict__ Wt,
    float* __restrict__ out,
    unsigned short* __restrict__ raw,
    float* __restrict__ psum,
    float* __restrict__ psq)
{
  __shared__ union {
    unsigned short b[3][BK * BN];                    // 3 x 16 KB bf16
    struct { float S[2][BN]; float Q[2][BN]; } st;   // 4 KB overlay
  } sm;
  __shared__ unsigned int offs[BM * 8];              // 4 KB

  const int tid = threadIdx.x;
  const int l   = tid & 63;
  const int w   = tid >> 6;       // 8 waves
  const int wr  = w >> 2;         // 0..1 (64-row strip)
  const int wc  = w & 3;          // 0..3 (64-col strip)
  const int lg  = l >> 4;
  const int lm  = l & 15;

  // XCD pairing: two n-halves of one m-panel adjacent on one XCD (A L2-shared)
  const int bid = blockIdx.x;
  const int xcd = bid & 7;
  const int j   = bid >> 3;
  const int mb  = xcd * 64 + (j >> 1);
  const int nh  = j & 1;
  const int n0  = nh * BN;
  const int m0  = mb * BM;
  const int pidx = mb * 2 + nh;

  for (int e = tid; e < BM * 8; e += 512)
    offs[e] = ((unsigned)neigh[(size_t)m0 * 8 + e]) << 8;
  __syncthreads();

  f32x4 acc[4][4];
#pragma unroll
  for (int i = 0; i < 4; ++i)
#pragma unroll
    for (int jj = 0; jj < 4; ++jj) acc[i][jj] = (f32x4){0.f, 0.f, 0.f, 0.f};

  // per-lane A rows: r_mi = wr*64 + mi*16 + lm  (block-local)
  const int r0 = (wr * 64 + lm) * 8;             // offs index base, mi=0
  unsigned o0, o1, o2, o3;                       // current-child row offsets
  unsigned p0, p1, p2, p3;                       // next-child row offsets

  // B: wave w covers LDS chunk pair q0=w*2 (as R16)
  const int q0 = w * 2;
  const unsigned short* bbase =
      Wt + n0 * 8 + (q0 >> 2) * 4096 + (q0 & 3) * 512 + l * 8;

  unsigned short *bA = sm.b[0], *bB = sm.b[1], *bC = sm.b[2];

  f32x4 XA[8], YA[8];   // 2-deep A register sets (4 frags x 2 f32x4)
  bf16x8 af[4];

  // A loads: frag mi covers rows wr*64+mi*16+0..15; lane (lg,lm): 8 floats
  // at k-offset j_*32 + lg*8 of row's child-slice.
#define AGS(j_, Q0_, Q1_, Q2_, Q3_, A_) do { \
    const f32x4* a0_ = reinterpret_cast<const f32x4*>(data + (Q0_) + (j_) * 32 + lg * 8); \
    const f32x4* a1_ = reinterpret_cast<const f32x4*>(data + (Q1_) + (j_) * 32 + lg * 8); \
    const f32x4* a2_ = reinterpret_cast<const f32x4*>(data + (Q2_) + (j_) * 32 + lg * 8); \
    const f32x4* a3_ = reinterpret_cast<const f32x4*>(data + (Q3_) + (j_) * 32 + lg * 8); \
    A_[0] = a0_[0]; A_[1] = a0_[1]; \
    A_[2] = a1_[0]; A_[3] = a1_[1]; \
    A_[4] = a2_[0]; A_[5] = a2_[1]; \
    A_[6] = a3_[0]; A_[7] = a3_[1]; \
  } while (0)

#define BD(T_, dst_) do { \
    const unsigned short* bs_ = bbase + (size_t)(T_) * 16384; \
    gload_lds16u(bs_,       (dst_) + q0 * 512); \
    gload_lds16u(bs_ + 512, (dst_) + q0 * 512 + 512); \
  } while (0)

#define PACK(A_) do { \
    af[0] = pack8(A_[0], A_[1]); \
    af[1] = pack8(A_[2], A_[3]); \
    af[2] = pack8(A_[4], A_[5]); \
    af[3] = pack8(A_[6], A_[7]); \
  } while (0)

#define MM(bP_) do { \
    _Pragma("unroll") \
    for (int ni_ = 0; ni_ < 4; ++ni_) { \
      bf16x8 bb_ = *reinterpret_cast<const bf16x8*>( \
          (bP_) + lg * 2048 + (wc * 64 + ni_ * 16 + lm) * 8); \
      _Pragma("unroll") \
      for (int mi_ = 0; mi_ < 4; ++mi_) \
        acc[mi_][ni_] = __builtin_amdgcn_mfma_f32_16x16x32_bf16(af[mi_], bb_, acc[mi_][ni_], 0, 0, 0); \
    } \
  } while (0)

  // one body; cn_, j_ compile-time. Issues exactly 18 vmem ops (16 A + 2 BD)
  // except in the final two bodies.
#define BODY(cn_, j_) do { \
    if ((cn_) == 7 && (j_) == 7) asm volatile("s_waitcnt vmcnt(0)" ::: "memory"); \
    else                         asm volatile("s_waitcnt vmcnt(18)" ::: "memory"); \
    asm volatile("s_waitcnt lgkmcnt(0)" ::: "memory"); \
    __builtin_amdgcn_s_barrier(); \
    asm volatile("" ::: "memory"); \
    if (!((cn_) == 7 && (j_) >= 6)) BD((cn_) * 8 + (j_) + 2, bC); \
    if ((j_) & 1) PACK(YA); else PACK(XA); \
    if ((j_) <= 5) { \
      if ((j_) & 1) AGS((j_) + 2, o0, o1, o2, o3, YA); \
      else          AGS((j_) + 2, o0, o1, o2, o3, XA); \
    } else if ((cn_) < 7) { \
      if ((j_) == 6) AGS(0, p0, p1, p2, p3, XA); \
      else           AGS(1, p0, p1, p2, p3, YA); \
    } \
    MM(bA); \
    asm volatile("" ::: "memory"); \
    { unsigned short* t_ = bA; bA = bB; bB = bC; bC = t_; } \
  } while (0)

  // ---- prologue: child-0 offsets; A(0)->X, A(1)->Y, B(0), B(1) in flight
  o0 = offs[r0];
  o1 = offs[r0 + 128];    // (mi=1) row +16 -> offs index +16*8
  o2 = offs[r0 + 256];
  o3 = offs[r0 + 384];
  AGS(0, o0, o1, o2, o3, XA);
  BD(0, sm.b[0]);
  AGS(1, o0, o1, o2, o3, YA);
  BD(1, sm.b[1]);

#pragma unroll 1
  for (int cn = 0; cn < 8; ++cn) {
    if (cn < 7) {
      p0 = offs[r0 + cn + 1];
      p1 = offs[r0 + 128 + cn + 1];
      p2 = offs[r0 + 256 + cn + 1];
      p3 = offs[r0 + 384 + cn + 1];
    }
    BODY(cn, 0); BODY(cn, 1); BODY(cn, 2); BODY(cn, 3);
    BODY(cn, 4); BODY(cn, 5); BODY(cn, 6); BODY(cn, 7);
    o0 = p0; o1 = p1; o2 = p2; o3 = p3;
  }

  // ---- epilogue 1: raw bf16 (big-ws) or fp32 out
  //      (C layout: col = lane&15, row = (lane>>4)*4 + reg)
  if (raw) {
#pragma unroll
    for (int mi = 0; mi < 4; ++mi) {
#pragma unroll
      for (int r = 0; r < 4; ++r) {
        size_t row = (size_t)(m0 + wr * 64 + mi * 16 + lg * 4 + r);
        unsigned short* rp = raw + row * COUT + n0 + wc * 64 + lm;
#pragma unroll
        for (int ni = 0; ni < 4; ++ni) rp[ni * 16] = f2bf(acc[mi][ni][r]);
      }
    }
  } else {
#pragma unroll
    for (int mi = 0; mi < 4; ++mi) {
#pragma unroll
      for (int r = 0; r < 4; ++r) {
        size_t row = (size_t)(m0 + wr * 64 + mi * 16 + lg * 4 + r);
        float* op = out + row * COUT + n0 + wc * 64 + lm;
#pragma unroll
        for (int ni = 0; ni < 4; ++ni) op[ni * 16] = acc[mi][ni][r];
      }
    }
  }

  // ---- epilogue 2: deterministic per-block column sums/sumsq (exact fp32)
  __syncthreads();   // all DMA retired (vmcnt(0) in final body) + reads done
#pragma unroll
  for (int ni = 0; ni < 4; ++ni) {
    float s1 = 0.f, s2 = 0.f;
#pragma unroll
    for (int mi = 0; mi < 4; ++mi)
#pragma unroll
      for (int r = 0; r < 4; ++r) { float v = acc[mi][ni][r]; s1 += v; s2 += v * v; }
    s1 += __shfl_xor(s1, 16, 64); s1 += __shfl_xor(s1, 32, 64);
    s2 += __shfl_xor(s2, 16, 64); s2 += __shfl_xor(s2, 32, 64);
    if (l < 16) {
      sm.st.S[wr][wc * 64 + ni * 16 + l] = s1;
      sm.st.Q[wr][wc * 64 + ni * 16 + l] = s2;
    }
  }
  __syncthreads();
  if (tid < BN) {
    psum[(size_t)pidx * BN + tid] = sm.st.S[0][tid] + sm.st.S[1][tid];
  } else {
    int c = tid - BN;
    psq[(size_t)pidx * BN + c] = sm.st.Q[0][c] + sm.st.Q[1][c];
  }
#undef AGS
#undef BD
#undef PACK
#undef MM
#undef BODY
}

// --- stats reduction, stage 1: partials [512 mb][2 nh][256] -> 64 per column
__global__ void reduce1_kernel(const float* __restrict__ psum, const float* __restrict__ psq,
                               float* __restrict__ p2) {
  int c = threadIdx.x, b = blockIdx.x;
  int h = c >> 8, crel = c & 255;
  float s = 0.f, q = 0.f;
#pragma unroll
  for (int jj = 0; jj < 8; ++jj) {
    size_t pi = (size_t)((b * 8 + jj) * 2 + h);
    s += psum[pi * 256 + crel];
    q += psq [pi * 256 + crel];
  }
  p2[b * 1024 + c] = s;
  p2[b * 1024 + 512 + c] = q;
}

// --- stats reduction, stage 2: mean/var -> per-column scale/shift
__global__ void reduce2_kernel(const float* __restrict__ p2,
                               const float* __restrict__ gamma,
                               const float* __restrict__ beta,
                               float* __restrict__ scsh) {
  int c = threadIdx.x;
  float s = 0.f, q = 0.f;
  for (int b = 0; b < 64; ++b) { s += p2[b * 1024 + c]; q += p2[b * 1024 + 512 + c]; }
  float mean = s * (1.f / 65536.f);
  float var  = q * (1.f / 65536.f) - mean * mean;
  float rs   = rsqrtf(var + 1e-5f);
  float sc   = gamma[c] * rs;
  scsh[c] = sc;
  scsh[COUT + c] = beta[c] - mean * sc;   // conv bias cancels in BN
}

// --- apply BN: raw bf16 -> out fp32 (big-ws path)
__global__ void bn_bf16_kernel(const unsigned short* __restrict__ raw,
                               float* __restrict__ out,
                               const float* __restrict__ scsh) {
  __shared__ float sc[COUT], sh[COUT];
  int t = threadIdx.x;
  sc[t] = scsh[t];
  sh[t] = scsh[COUT + t];
  __syncthreads();
  const bf16x8* r8 = reinterpret_cast<const bf16x8*>(raw);
  const size_t total  = (size_t)N_OUT * COUT / 8;
  const size_t stride = (size_t)gridDim.x * blockDim.x;
  for (size_t i = (size_t)blockIdx.x * blockDim.x + t; i < total; i += stride) {
    bf16x8 v = r8[i];
    int c0 = ((int)(i & 63)) * 8;
    f32x4 o0, o1;
    o0.x = bf2f((unsigned short)v[0]) * sc[c0]     + sh[c0];
    o0.y = bf2f((unsigned short)v[1]) * sc[c0 + 1] + sh[c0 + 1];
    o0.z = bf2f((unsigned short)v[2]) * sc[c0 + 2] + sh[c0 + 2];
    o0.w = bf2f((unsigned short)v[3]) * sc[c0 + 3] + sh[c0 + 3];
    o1.x = bf2f((unsigned short)v[4]) * sc[c0 + 4] + sh[c0 + 4];
    o1.y = bf2f((unsigned short)v[5]) * sc[c0 + 5] + sh[c0 + 5];
    o1.z = bf2f((unsigned short)v[6]) * sc[c0 + 6] + sh[c0 + 6];
    o1.w = bf2f((unsigned short)v[7]) * sc[c0 + 7] + sh[c0 + 7];
    f32x4* op = reinterpret_cast<f32x4*>(out + i * 8);
    op[0] = o0;
    op[1] = o1;
  }
}

// --- apply BN in-place on fp32 out (fallback path)
__global__ void bn_kernel(float* __restrict__ out, const float* __restrict__ scsh) {
  __shared__ float sc[COUT], sh[COUT];
  int t = threadIdx.x;
  sc[t] = scsh[t];
  sh[t] = scsh[COUT + t];
  __syncthreads();
  f32x4* o4 = reinterpret_cast<f32x4*>(out);
  const size_t total  = (size_t)N_OUT * COUT / 4;
  const size_t stride = (size_t)gridDim.x * blockDim.x;
  for (size_t i = (size_t)blockIdx.x * blockDim.x + t; i < total; i += stride) {
    f32x4 v = o4[i];
    int c = ((int)(i & 127)) * 4;
    v.x = v.x * sc[c]     + sh[c];
    v.y = v.y * sc[c + 1] + sh[c + 1];
    v.z = v.z * sc[c + 2] + sh[c + 2];
    v.w = v.w * sc[c + 3] + sh[c + 3];
    o4[i] = v;
  }
}

extern "C" void kernel_launch(void* const* d_in, const int* in_sizes, int n_in,
                              void* d_out, int out_size, void* d_ws, size_t ws_size,
                              hipStream_t stream) {
  const float* data   = (const float*)d_in[0];
  const float* weight = (const float*)d_in[1];
  const float* gamma  = (const float*)d_in[3];
  const float* beta   = (const float*)d_in[4];
  const int*   neigh  = (const int*)d_in[5];
  float* out = (float*)d_out;

  char* ws = (char*)d_ws;
  unsigned short* Wt = (unsigned short*)ws;                        // 2 MB
  float* psum = (float*)(ws + (2u << 20));                         // 1 MB
  float* psq  = (float*)(ws + (3u << 20));                         // 1 MB
  float* p2   = (float*)(ws + (4u << 20));                         // 256 KB
  float* scsh = (float*)(ws + (4u << 20) + (256u << 10));          // 4 KB

  // bf16 intermediate needs 64 MB at offset 8 MB -> requires ws >= 72 MB
  const bool big = ws_size >= (72ull << 20);
  unsigned short* raw = big ? (unsigned short*)(ws + (8ull << 20)) : nullptr;

  wprep_kernel<<<512, 256, 0, stream>>>(weight, Wt);
  gemm_kernel<<<1024, 512, 0, stream>>>(data, neigh, Wt, out, raw, psum, psq);
  reduce1_kernel<<<64, 512, 0, stream>>>(psum, psq, p2);
  reduce2_kernel<<<1, 512, 0, stream>>>(p2, gamma, beta, scsh);
  if (big) bn_bf16_kernel<<<2048, 512, 0, stream>>>(raw, out, scsh);
  else     bn_kernel<<<2048, 512, 0, stream>>>(out, scsh);
}

// Round 18
// 258.124 us; speedup vs baseline: 2.4689x; 2.4689x over previous
//
#include <hip/hip_runtime.h>
#include <hip/hip_bf16.h>

typedef __attribute__((ext_vector_type(8))) short bf16x8;
typedef __attribute__((ext_vector_type(4))) float f32x4;

#define N_OUT 65536
#define CIN   256
#define COUT  512
#define BM    128
#define BN    256
#define BK    32
#define NKS   64    // 2048 / 32 K-steps

__device__ __forceinline__ unsigned short f2bf(float f) {
  union { __hip_bfloat16 h; unsigned short u; } c;
  c.h = __float2bfloat16(f);
  return c.u;
}

__device__ __forceinline__ float bf2f(unsigned short u) {
  union { unsigned int i; float f; } c;
  c.i = ((unsigned int)u) << 16;
  return c.f;
}

__device__ __forceinline__ bf16x8 pack8(f32x4 a, f32x4 b) {
  unsigned short u[8];
  u[0] = f2bf(a.x); u[1] = f2bf(a.y); u[2] = f2bf(a.z); u[3] = f2bf(a.w);
  u[4] = f2bf(b.x); u[5] = f2bf(b.y); u[6] = f2bf(b.z); u[7] = f2bf(b.w);
  return *reinterpret_cast<bf16x8*>(u);
}

__device__ __forceinline__ void gload_lds16u(const unsigned short* g, unsigned short* l) {
  __builtin_amdgcn_global_load_lds(
      (const __attribute__((address_space(1))) void*)g,
      (__attribute__((address_space(3))) void*)l, 16, 0, 0);
}

// --- weight prep: W[k][n] f32 -> Wt bf16 tiled [kb][slot][n][w]:
//     Wt[kb*16384 + s*4096 + n*8 + w] = bf16(W[(kb*32 + s*8 + w)*512 + n])
__global__ void wprep_kernel(const float* __restrict__ W, unsigned short* __restrict__ Wt) {
  int idx = blockIdx.x * blockDim.x + threadIdx.x;
  if (idx >= 64 * 4 * COUT) return;
  int n  = idx & (COUT - 1);
  int s  = (idx >> 9) & 3;
  int kb = idx >> 11;
  unsigned short tmp[8];
#pragma unroll
  for (int w = 0; w < 8; ++w)
    tmp[w] = f2bf(W[(size_t)(kb * 32 + s * 8 + w) * COUT + n]);
  *reinterpret_cast<bf16x8*>(Wt + ((size_t)kb * 16384 + s * 4096 + n * 8)) =
      *reinterpret_cast<bf16x8*>(tmp);
}

// --- main GEMM (best measured structure, R11/R14/R16): 128x256 blocks, 8
//     waves (2 row-strips x 4 col-strips), wave tile 64x64. A: reg-staged
//     f32 -> bf16 ds_write into 3-ring swizzled LDS; B: global_load_lds
//     3-ring. ONE barrier/step, counted vmcnt (never drains in steady
//     state), staging issued post-barrier. 2 blocks/CU (LDS 76KB, VGPR 116).
__global__ __launch_bounds__(512, 4) void gemm_kernel(
    const float* __restrict__ data,
    const int*   __restrict__ neigh,
    const unsigned short* __restrict__ Wt,
    float* __restrict__ out,
    unsigned short* __restrict__ raw,
    float* __restrict__ psum,
    float* __restrict__ psq)
{
  __shared__ union {
    struct {
      unsigned short a[3][BM * BK];   // 3 x 8 KB bf16, 16B-slot XOR swizzle
      unsigned short b[3][BK * BN];   // 3 x 16 KB bf16, [slot][256 n][8]
    } r;                              // 72 KB
    struct { float S[2][BN]; float Q[2][BN]; } st;   // 4 KB overlay
  } sm;
  __shared__ unsigned int offs[BM * 8];   // 4 KB

  const int tid = threadIdx.x;
  const int l   = tid & 63;
  const int w   = tid >> 6;       // 8 waves
  const int wr  = w >> 2;         // 0..1 (64-row strip)
  const int wc  = w & 3;          // 0..3 (64-col strip)
  const int lg  = l >> 4;
  const int lm  = l & 15;

  // XCD pairing: two n-halves of one m-panel adjacent on one XCD (A L2-shared)
  const int bid = blockIdx.x;
  const int xcd = bid & 7;
  const int j   = bid >> 3;
  const int mb  = xcd * 64 + (j >> 1);
  const int nh  = j & 1;
  const int n0  = nh * BN;
  const int m0  = mb * BM;
  const int pidx = mb * 2 + nh;

  for (int e = tid; e < BM * 8; e += 512)
    offs[e] = ((unsigned)neigh[(size_t)m0 * 8 + e]) << 8;
  __syncthreads();

  f32x4 acc[4][4];
#pragma unroll
  for (int i = 0; i < 4; ++i)
#pragma unroll
    for (int jj = 0; jj < 4; ++jj) acc[i][jj] = (f32x4){0.f, 0.f, 0.f, 0.f};

  // A staging: thread -> (row = tid>>2, 16B chunk = tid&3); swizzled slot
  const int arow8 = (tid >> 2) * 8;
  const int achk8 = (tid & 3) * 8;
  const int awoff = (tid >> 2) * BK +
                    (((tid & 3) ^ ((tid >> 2) & 3) ^ ((tid >> 4) & 3)) << 3);
  // A frag read: slot = lg ^ (lm&3) ^ ((lm>>2)&3)  (bank-balanced)
  const int aroff = (lg ^ (lm & 3) ^ ((lm >> 2) & 3)) << 3;

  // B: wave w covers LDS chunk pair q0=w*2 (slot w>>1, n-part)
  const int q0 = w * 2;
  const unsigned short* bbase =
      Wt + n0 * 8 + (q0 >> 2) * 4096 + (q0 & 3) * 512 + l * 8;

  // ring pointers: xA = read buf(t%3), xC = write buf((t+2)%3)
  unsigned short *aA = sm.r.a[0], *aB = sm.r.a[1], *aC = sm.r.a[2];
  unsigned short *bA = sm.r.b[0], *bB = sm.r.b[1], *bC = sm.r.b[2];

  f32x4 X0, X1, Y0, Y1;

#define AG(T_, S0_, S1_) do { \
    int cn_ = (T_) >> 3, k0_ = ((T_) & 7) * BK; \
    const f32x4* p_ = reinterpret_cast<const f32x4*>(data + offs[arow8 + cn_] + k0_ + achk8); \
    S0_ = p_[0]; S1_ = p_[1]; \
  } while (0)

#define BD(T_, dst_) do { \
    const unsigned short* bs_ = bbase + (size_t)(T_) * 16384; \
    gload_lds16u(bs_,       (dst_) + q0 * 512); \
    gload_lds16u(bs_ + 512, (dst_) + q0 * 512 + 512); \
  } while (0)

#define COMPUTE(aP_, bP_) do { \
    bf16x8 af_[4]; \
    _Pragma("unroll") \
    for (int mi_ = 0; mi_ < 4; ++mi_) \
      af_[mi_] = *reinterpret_cast<const bf16x8*>( \
          (aP_) + (wr * 64 + mi_ * 16 + lm) * BK + aroff); \
    _Pragma("unroll") \
    for (int ni_ = 0; ni_ < 4; ++ni_) { \
      bf16x8 bb_ = *reinterpret_cast<const bf16x8*>( \
          (bP_) + lg * 2048 + (wc * 64 + ni_ * 16 + lm) * 8); \
      _Pragma("unroll") \
      for (int mi_ = 0; mi_ < 4; ++mi_) \
        acc[mi_][ni_] = __builtin_amdgcn_mfma_f32_16x16x32_bf16(af_[mi_], bb_, acc[mi_][ni_], 0, 0, 0); \
    } \
  } while (0)

#define BODY(t_, S0_, S1_) do { \
    if ((t_) <= NKS - 3)      asm volatile("s_waitcnt vmcnt(4)" ::: "memory"); \
    else if ((t_) == NKS - 2) asm volatile("s_waitcnt vmcnt(2)" ::: "memory"); \
    else                      asm volatile("s_waitcnt vmcnt(0)" ::: "memory"); \
    asm volatile("s_waitcnt lgkmcnt(0)" ::: "memory"); \
    __builtin_amdgcn_s_barrier(); \
    asm volatile("" ::: "memory"); \
    if ((t_) <= NKS - 3) { \
      *reinterpret_cast<bf16x8*>(aC + awoff) = pack8(S0_, S1_);  /* A(t+2) */ \
      BD((t_) + 2, bC); \
    } \
    if ((t_) <= NKS - 5) AG((t_) + 4, S0_, S1_); \
    COMPUTE(aA, bA); \
    asm volatile("" ::: "memory"); \
    { unsigned short* t0_ = aA; aA = aB; aB = aC; aC = t0_; } \
    { unsigned short* t1_ = bA; bA = bB; bB = bC; bC = t1_; } \
  } while (0)

  // ---- prologue: A(0),A(1) converted into bufs 0,1; B(0),B(1) DMA'd;
  //      A(2),A(3) loads in flight. (flight at loop top: AG2,BD0,AG3,BD1 = 8)
  AG(0, X0, X1);
  AG(1, Y0, Y1);
  asm volatile("s_waitcnt vmcnt(2)" ::: "memory");
  *reinterpret_cast<bf16x8*>(sm.r.a[0] + awoff) = pack8(X0, X1);
  AG(2, X0, X1);
  BD(0, sm.r.b[0]);
  asm volatile("s_waitcnt vmcnt(4)" ::: "memory");
  *reinterpret_cast<bf16x8*>(sm.r.a[1] + awoff) = pack8(Y0, Y1);
  AG(3, Y0, Y1);
  BD(1, sm.r.b[1]);

#pragma unroll 1
  for (int t = 0; t < NKS; t += 2) {
    BODY(t,     X0, X1);
    BODY(t + 1, Y0, Y1);
  }

  // ---- epilogue 1: raw bf16 (big-ws path) or fp32 out
  //      (C layout: col = lane&15, row = (lane>>4)*4 + reg)
  if (raw) {
#pragma unroll
    for (int mi = 0; mi < 4; ++mi) {
#pragma unroll
      for (int r = 0; r < 4; ++r) {
        size_t row = (size_t)(m0 + wr * 64 + mi * 16 + lg * 4 + r);
        unsigned short* rp = raw + row * COUT + n0 + wc * 64 + lm;
#pragma unroll
        for (int ni = 0; ni < 4; ++ni) rp[ni * 16] = f2bf(acc[mi][ni][r]);
      }
    }
  } else {
#pragma unroll
    for (int mi = 0; mi < 4; ++mi) {
#pragma unroll
      for (int r = 0; r < 4; ++r) {
        size_t row = (size_t)(m0 + wr * 64 + mi * 16 + lg * 4 + r);
        float* op = out + row * COUT + n0 + wc * 64 + lm;
#pragma unroll
        for (int ni = 0; ni < 4; ++ni) op[ni * 16] = acc[mi][ni][r];
      }
    }
  }

  // ---- epilogue 2: deterministic per-block column sums/sumsq (exact fp32)
  __syncthreads();   // all DMA retired (vmcnt(0) at last step) + reads done
#pragma unroll
  for (int ni = 0; ni < 4; ++ni) {
    float s1 = 0.f, s2 = 0.f;
#pragma unroll
    for (int mi = 0; mi < 4; ++mi)
#pragma unroll
      for (int r = 0; r < 4; ++r) { float v = acc[mi][ni][r]; s1 += v; s2 += v * v; }
    s1 += __shfl_xor(s1, 16, 64); s1 += __shfl_xor(s1, 32, 64);
    s2 += __shfl_xor(s2, 16, 64); s2 += __shfl_xor(s2, 32, 64);
    if (l < 16) {
      sm.st.S[wr][wc * 64 + ni * 16 + l] = s1;
      sm.st.Q[wr][wc * 64 + ni * 16 + l] = s2;
    }
  }
  __syncthreads();
  if (tid < BN) {
    psum[(size_t)pidx * BN + tid] = sm.st.S[0][tid] + sm.st.S[1][tid];
  } else {
    int c = tid - BN;
    psq[(size_t)pidx * BN + c] = sm.st.Q[0][c] + sm.st.Q[1][c];
  }
#undef AG
#undef BD
#undef COMPUTE
#undef BODY
}

// --- stats reduction, stage 1: partials [512 mb][2 nh][256] -> 64 per column
__global__ void reduce1_kernel(const float* __restrict__ psum, const float* __restrict__ psq,
                               float* __restrict__ p2) {
  int c = threadIdx.x, b = blockIdx.x;
  int h = c >> 8, crel = c & 255;
  float s = 0.f, q = 0.f;
#pragma unroll
  for (int jj = 0; jj < 8; ++jj) {
    size_t pi = (size_t)((b * 8 + jj) * 2 + h);
    s += psum[pi * 256 + crel];
    q += psq [pi * 256 + crel];
  }
  p2[b * 1024 + c] = s;
  p2[b * 1024 + 512 + c] = q;
}

// --- stats reduction, stage 2: mean/var -> per-column scale/shift
__global__ void reduce2_kernel(const float* __restrict__ p2,
                               const float* __restrict__ gamma,
                               const float* __restrict__ beta,
                               float* __restrict__ scsh) {
  int c = threadIdx.x;
  float s = 0.f, q = 0.f;
  for (int b = 0; b < 64; ++b) { s += p2[b * 1024 + c]; q += p2[b * 1024 + 512 + c]; }
  float mean = s * (1.f / 65536.f);
  float var  = q * (1.f / 65536.f) - mean * mean;
  float rs   = rsqrtf(var + 1e-5f);
  float sc   = gamma[c] * rs;
  scsh[c] = sc;
  scsh[COUT + c] = beta[c] - mean * sc;   // conv bias cancels in BN
}

// --- apply BN: raw bf16 -> out fp32 (big-ws path; 67MB read + 134MB write)
__global__ void bn_bf16_kernel(const unsigned short* __restrict__ raw,
                               float* __restrict__ out,
                               const float* __restrict__ scsh) {
  __shared__ float sc[COUT], sh[COUT];
  int t = threadIdx.x;
  sc[t] = scsh[t];
  sh[t] = scsh[COUT + t];
  __syncthreads();
  const bf16x8* r8 = reinterpret_cast<const bf16x8*>(raw);
  const size_t total  = (size_t)N_OUT * COUT / 8;
  const size_t stride = (size_t)gridDim.x * blockDim.x;
  for (size_t i = (size_t)blockIdx.x * blockDim.x + t; i < total; i += stride) {
    bf16x8 v = r8[i];
    int c0 = ((int)(i & 63)) * 8;
    f32x4 o0, o1;
    o0.x = bf2f((unsigned short)v[0]) * sc[c0]     + sh[c0];
    o0.y = bf2f((unsigned short)v[1]) * sc[c0 + 1] + sh[c0 + 1];
    o0.z = bf2f((unsigned short)v[2]) * sc[c0 + 2] + sh[c0 + 2];
    o0.w = bf2f((unsigned short)v[3]) * sc[c0 + 3] + sh[c0 + 3];
    o1.x = bf2f((unsigned short)v[4]) * sc[c0 + 4] + sh[c0 + 4];
    o1.y = bf2f((unsigned short)v[5]) * sc[c0 + 5] + sh[c0 + 5];
    o1.z = bf2f((unsigned short)v[6]) * sc[c0 + 6] + sh[c0 + 6];
    o1.w = bf2f((unsigned short)v[7]) * sc[c0 + 7] + sh[c0 + 7];
    f32x4* op = reinterpret_cast<f32x4*>(out + i * 8);
    op[0] = o0;
    op[1] = o1;
  }
}

// --- apply BN in-place on fp32 out (fallback path)
__global__ void bn_kernel(float* __restrict__ out, const float* __restrict__ scsh) {
  __shared__ float sc[COUT], sh[COUT];
  int t = threadIdx.x;
  sc[t] = scsh[t];
  sh[t] = scsh[COUT + t];
  __syncthreads();
  f32x4* o4 = reinterpret_cast<f32x4*>(out);
  const size_t total  = (size_t)N_OUT * COUT / 4;
  const size_t stride = (size_t)gridDim.x * blockDim.x;
  for (size_t i = (size_t)blockIdx.x * blockDim.x + t; i < total; i += stride) {
    f32x4 v = o4[i];
    int c = ((int)(i & 127)) * 4;
    v.x = v.x * sc[c]     + sh[c];
    v.y = v.y * sc[c + 1] + sh[c + 1];
    v.z = v.z * sc[c + 2] + sh[c + 2];
    v.w = v.w * sc[c + 3] + sh[c + 3];
    o4[i] = v;
  }
}

extern "C" void kernel_launch(void* const* d_in, const int* in_sizes, int n_in,
                              void* d_out, int out_size, void* d_ws, size_t ws_size,
                              hipStream_t stream) {
  const float* data   = (const float*)d_in[0];
  const float* weight = (const float*)d_in[1];
  const float* gamma  = (const float*)d_in[3];
  const float* beta   = (const float*)d_in[4];
  const int*   neigh  = (const int*)d_in[5];
  float* out = (float*)d_out;

  char* ws = (char*)d_ws;
  unsigned short* Wt = (unsigned short*)ws;                        // 2 MB
  float* psum = (float*)(ws + (2u << 20));                         // 1 MB
  float* psq  = (float*)(ws + (3u << 20));                         // 1 MB
  float* p2   = (float*)(ws + (4u << 20));                         // 256 KB
  float* scsh = (float*)(ws + (4u << 20) + (256u << 10));          // 4 KB

  // bf16 intermediate needs 64 MB at offset 8 MB -> requires ws >= 72 MB
  const bool big = ws_size >= (72ull << 20);
  unsigned short* raw = big ? (unsigned short*)(ws + (8ull << 20)) : nullptr;

  wprep_kernel<<<512, 256, 0, stream>>>(weight, Wt);
  gemm_kernel<<<1024, 512, 0, stream>>>(data, neigh, Wt, out, raw, psum, psq);
  reduce1_kernel<<<64, 512, 0, stream>>>(psum, psq, p2);
  reduce2_kernel<<<1, 512, 0, stream>>>(p2, gamma, beta, scsh);
  if (big) bn_bf16_kernel<<<2048, 512, 0, stream>>>(raw, out, scsh);
  else     bn_kernel<<<2048, 512, 0, stream>>>(out, scsh);
}